// Round 11
// baseline (519.605 us; speedup 1.0000x reference)
//
#include <hip/hip_runtime.h>
#include <hip/hip_bf16.h>

typedef __attribute__((ext_vector_type(8))) short short8;
typedef __attribute__((ext_vector_type(4))) float f32x4;

// pack 8 fp32 -> 8 bf16 (RNE) as one short8 (4 VGPRs)
__device__ __forceinline__ short8 pack8(const f32x4& a, const f32x4& b) {
    union { __hip_bfloat162 h[4]; short8 s; } u;
    u.h[0] = __float22bfloat162_rn(make_float2(a[0], a[1]));
    u.h[1] = __float22bfloat162_rn(make_float2(a[2], a[3]));
    u.h[2] = __float22bfloat162_rn(make_float2(b[0], b[1]));
    u.h[3] = __float22bfloat162_rn(make_float2(b[2], b[3]));
    return u.s;
}

// r2..r7-proven involution swizzle (fallback kernel only)
__device__ __forceinline__ int swz4(int g) { return g ^ (((g >> 4) & 3) << 1); }

// ============================================================================
// Kernel 1 (r8/r9-proven): fp32 -> bf16 conversion + MFMA-granule relayout.
// Granule (idx, ks) = 1KB: lane l holds row idx*16+(l&15), k ks*32+(l>>4)*8..+8.
// W1b: [km][f 0..31][ks 0..15]; Xb (at +134217728 shorts): [mf 0..63][ks].
// ============================================================================
__global__ __launch_bounds__(256)
void ens_cvt(const float* __restrict__ X, const float* __restrict__ W1,
             short* __restrict__ WS)
{
    const int t = threadIdx.x, lane = t & 63, wv = t >> 6;
    const int g = blockIdx.x * 4 + wv;
    const int row16 = lane & 15, koct = lane >> 4;
    const float* src;
    short* dst;
    if (blockIdx.x < 4096) {                       // W1: g = km*32 + f
        const int km = g >> 5, f = g & 31;
        src = W1 + (size_t)km * 262144 + (size_t)(f * 16 + row16) * 512 + koct * 8;
        dst = WS + (size_t)km * 262144 + (size_t)(f * 16) * 512 + lane * 8;
    } else {                                       // X: mf = g - 16384 (0..63)
        const int mf = g - 16384;
        src = X + (size_t)(mf * 16 + row16) * 512 + koct * 8;
        dst = WS + 134217728ull + (size_t)(mf * 16) * 512 + lane * 8;
    }
#pragma unroll
    for (int ks = 0; ks < 16; ++ks) {
        f32x4 a = *(const f32x4*)(src + ks * 32);
        f32x4 b = *(const f32x4*)(src + ks * 32 + 4);
        *(short8*)(dst + ks * 512) = pack8(a, b);
    }
}

// ============================================================================
// Kernel 2: DIRECT-LOAD bf16 GEMM — no LDS, no barriers, no waitcnt asm in
// the K-loop. Pre-permuted granules make every MFMA fragment a coalesced
// global_load_dwordx4 (granule + lane*8 shorts). Loads ride the VMEM pipe
// (compiler emits exact per-register counted vmcnt); MFMA rides the matrix
// pipe; the two overlap within and across the 2 waves/SIMD. A granules are
// read by 4 waves (same wm), B by 2 (same wn-group) -> L1/L2 serve re-reads;
// X region (1MB) is L2-resident; W1b slice shared by the 4 adjacent mt-blocks
// on the same XCD (swizzle).
// Pipeline: two named register sets P,Q (rule #20: static indexing), rotated:
//   MM(P,s) ; LOAD(P,s+2) ; MM(Q,s+1) ; LOAD(Q,s+3)
// so each set has >= one full 32-MFMA burst (~500 cyc) + VALU in flight
// before consumption. Registers: acc 128 + sets 96 + addr ~20 ~= 245.
// ============================================================================
#define LOADSET(AV, BV, POFF)                                                 \
  do {                                                                        \
    _Pragma("unroll") for (int mi = 0; mi < 8; ++mi)                          \
        AV[mi] = *(const short8*)(pa + mi * 8192 + (POFF));                   \
    _Pragma("unroll") for (int pp = 0; pp < 4; ++pp)                          \
        BV[pp] = *(const short8*)(pb + pp * 8192 + (POFF));                   \
  } while (0)

#define MM(AV, BV)                                                            \
  do {                                                                        \
    __builtin_amdgcn_s_setprio(1);                                            \
    _Pragma("unroll") for (int mi = 0; mi < 8; ++mi)                          \
        _Pragma("unroll") for (int pp = 0; pp < 4; ++pp)                      \
            acc[mi][pp] = __builtin_amdgcn_mfma_f32_16x16x32_bf16(            \
                AV[mi], BV[pp], acc[mi][pp], 0, 0, 0);                        \
    __builtin_amdgcn_s_setprio(0);                                            \
  } while (0)

__global__ __launch_bounds__(512, 2)
void ens_gemm_direct(const short* __restrict__ Xb, const short* __restrict__ W1b,
                     const float* __restrict__ B1, const float* __restrict__ W2,
                     const float* __restrict__ B2, float* __restrict__ out)
{
    __shared__ float lout[1024];   // epilogue only (4 KB)
    const int t    = threadIdx.x;
    const int lane = t & 63;
    const int wv   = t >> 6;
    const int wm   = wv >> 2;     // 0..1
    const int wn   = wv & 3;      // 0..3

    // XCD-aware decode: 8 blocks of the same km adjacent on one XCD.
    const int bb  = blockIdx.x;
    const int xcd = bb & 7;
    const int j   = bb >> 3;
    const int km  = xcd * 64 + (j >> 3);   // 0..511
    const int sub = j & 7;
    const int mt  = sub >> 1;              // 0..3 (256-row batch tile)
    const int nt  = sub & 1;               // 0..1 (256-col n half)

    // Fragment source pointers (per lane). Wave's A rows: wm*128 + mi*16;
    // B rows: nt*256 + (wn*4+pp)*16. Granule (idx, ks) at idx*8192 + ks*512.
    const short* pa = Xb + (size_t)(mt * 16 + wm * 8) * 8192 + lane * 8;
    const short* pb = W1b + (size_t)km * 262144 +
                      (size_t)(nt * 16 + wn * 4) * 8192 + lane * 8;

    f32x4 acc[8][4];
#pragma unroll
    for (int i = 0; i < 8; ++i)
#pragma unroll
        for (int p = 0; p < 4; ++p)
            acc[i][p] = (f32x4)0.0f;

    short8 avP[8], bvP[4], avQ[8], bvQ[4];

    // prologue: fill both sets (steps 0,1); advance to step 2
    LOADSET(avP, bvP, 0);
    LOADSET(avQ, bvQ, 512);
    pa += 1024; pb += 1024;

#pragma unroll 1
    for (int kt = 0; kt < 7; ++kt) {
        MM(avP, bvP);              // consume step 2kt   (waits only on P)
        LOADSET(avP, bvP, 0);      // reload P with step 2kt+2
        MM(avQ, bvQ);              // consume step 2kt+1 (P' stays in flight)
        LOADSET(avQ, bvQ, 512);    // reload Q with step 2kt+3
        pa += 1024; pb += 1024;
    }
    MM(avP, bvP);                  // step 14
    MM(avQ, bvQ);                  // step 15

    // ---- fused epilogue (r6-proven): relu + dot(W2) partials + scatter ----
    const int nc = lane & 15;
    const int kq = lane >> 4;
    float b1v[4], w2v[4];
#pragma unroll
    for (int pp = 0; pp < 4; ++pp) {
        int n = nt * 256 + (wn * 4 + pp) * 16 + nc;
        b1v[pp] = B1[km * 512 + n];
        w2v[pp] = W2[km * 512 + n];
    }

#pragma unroll
    for (int i = 0; i < 8; ++i) {
#pragma unroll
        for (int r = 0; r < 4; ++r) {
            float s = 0.f;
#pragma unroll
            for (int pp = 0; pp < 4; ++pp) {
                float h = acc[i][pp][r] + b1v[pp];
                h = h > 0.f ? h : 0.f;
                s += h * w2v[pp];
            }
#pragma unroll
            for (int d = 1; d < 16; d <<= 1)
                s += __shfl_xor(s, d, 64);
            if (nc == 0) {
                int row = wm * 128 + i * 16 + kq * 4 + r;
                lout[row * 4 + wn] = s;
            }
        }
    }
    __syncthreads();
    if (t < 256) {
        float s = lout[t * 4 + 0] + lout[t * 4 + 1] + lout[t * 4 + 2] + lout[t * 4 + 3];
        if (nt == 0) s += B2[km];
        int b = mt * 256 + t;
        // out[b, e, o] with k = o*E + e  ->  flat b*512 + (km%8)*64 + (km/8)
        atomicAdd(out + (size_t)b * 512 + (km & 7) * 64 + (km >> 3), s);
    }
}

// ============================================================================
// Fallback (r6 verbatim, 428 µs): used when ws_size < 269,484,032 bytes.
// ============================================================================
#define FISSUE(S, BASE, KT1)                                                  \
  do {                                                                        \
    const float* q_ = (BASE) + (KT1) * 64;                                    \
    S[0] = *(const f32x4*)q_;          S[1] = *(const f32x4*)(q_ + 4);        \
    S[2] = *(const f32x4*)(q_ + 32);   S[3] = *(const f32x4*)(q_ + 36);       \
    const float* q2_ = q_ + 65536;                                            \
    S[4] = *(const f32x4*)q2_;         S[5] = *(const f32x4*)(q2_ + 4);       \
    S[6] = *(const f32x4*)(q2_ + 32);  S[7] = *(const f32x4*)(q2_ + 36);      \
  } while (0)

#define FWRITEB(S, WB, OPOFF)                                                 \
  do {                                                                        \
    char* d0_ = (WB) + (OPOFF) + wfrag;                                       \
    *(short8*)d0_ = pack8(S[0], S[1]);                                        \
    *(short8*)(d0_ + 1024) = pack8(S[2], S[3]);                               \
    char* d1_ = d0_ + 16384;                                                  \
    *(short8*)d1_ = pack8(S[4], S[5]);                                        \
    *(short8*)(d1_ + 1024) = pack8(S[6], S[7]);                               \
  } while (0)

#define FKK(RB, KKV)                                                          \
  do {                                                                        \
    _Pragma("unroll") for (int mi = 0; mi < 8; ++mi)                          \
        av[mi] = *(const short8*)((RB) +                                      \
            (((wm * 8 + mi) * 2 + (KKV)) << 10) + rdo);                       \
    _Pragma("unroll") for (int pp = 0; pp < 4; ++pp)                          \
        bv[pp] = *(const short8*)((RB) + 32768 +                              \
            (((wn * 4 + pp) * 2 + (KKV)) << 10) + rdo);                       \
    __builtin_amdgcn_s_setprio(1);                                            \
    _Pragma("unroll") for (int mi = 0; mi < 8; ++mi)                          \
        _Pragma("unroll") for (int pp = 0; pp < 4; ++pp)                      \
            acc[mi][pp] = __builtin_amdgcn_mfma_f32_16x16x32_bf16(            \
                av[mi], bv[pp], acc[mi][pp], 0, 0, 0);                        \
    __builtin_amdgcn_s_setprio(0);                                            \
  } while (0)

#define FPRO_WRITE(TT, ROFF)                                                  \
  do {                                                                        \
    short8 a_ = pack8(TT[0], TT[1]);                                          \
    short8 b_ = pack8(TT[2], TT[3]);                                          \
    char* d_ = smem + (ROFF) + wfrag;                                         \
    *(short8*)d_ = a_;                                                        \
    *(short8*)(d_ + 1024) = b_;                                               \
  } while (0)

__global__ __launch_bounds__(512, 2)
void ens_mlp_fallback(const float* __restrict__ X,
                      const float* __restrict__ W1,
                      const float* __restrict__ B1,
                      const float* __restrict__ W2,
                      const float* __restrict__ B2,
                      float* __restrict__ out)
{
    extern __shared__ char smem[];
    const int t    = threadIdx.x;
    const int lane = t & 63;
    const int wv   = t >> 6;
    const int wm   = wv >> 2;
    const int wn   = wv & 3;

    const int bb  = blockIdx.x;
    const int xcd = bb & 7;
    const int j   = bb >> 3;
    const int km  = xcd * 64 + (j >> 3);
    const int sub = j & 7;
    const int mt  = sub >> 1;
    const int nt  = sub & 1;

    const float* __restrict__ W1k = W1 + (size_t)km * (512 * 512);

    const int lr = t >> 2;
    const int c  = t & 3;
    const float* As = X   + (size_t)(mt * 256 + lr) * 512 + c * 8;
    const float* Bs = W1k + (size_t)(nt * 256 + lr) * 512 + c * 8;
    const int wfrag = ((lr >> 4) << 11) + (swz4((c << 4) | (lr & 15)) << 4);
    const int rdo   = swz4(lane) << 4;

    {
        f32x4 t0[4], t1[4], t2[4], t3[4];
        const float* q;
        q = As;          t0[0]=*(const f32x4*)q; t0[1]=*(const f32x4*)(q+4); t0[2]=*(const f32x4*)(q+32); t0[3]=*(const f32x4*)(q+36);
        q = As + 65536;  t1[0]=*(const f32x4*)q; t1[1]=*(const f32x4*)(q+4); t1[2]=*(const f32x4*)(q+32); t1[3]=*(const f32x4*)(q+36);
        q = Bs;          t2[0]=*(const f32x4*)q; t2[1]=*(const f32x4*)(q+4); t2[2]=*(const f32x4*)(q+32); t2[3]=*(const f32x4*)(q+36);
        q = Bs + 65536;  t3[0]=*(const f32x4*)q; t3[1]=*(const f32x4*)(q+4); t3[2]=*(const f32x4*)(q+32); t3[3]=*(const f32x4*)(q+36);
        asm volatile("s_waitcnt vmcnt(12)" ::: "memory"); FPRO_WRITE(t0, 0);
        asm volatile("s_waitcnt vmcnt(8)"  ::: "memory"); FPRO_WRITE(t1, 16384);
        asm volatile("s_waitcnt vmcnt(4)"  ::: "memory"); FPRO_WRITE(t2, 32768);
        asm volatile("s_waitcnt vmcnt(0)"  ::: "memory"); FPRO_WRITE(t3, 49152);
        asm volatile("s_waitcnt lgkmcnt(0)" ::: "memory");
        __builtin_amdgcn_sched_barrier(0);
        __builtin_amdgcn_s_barrier();
    }

    f32x4 acc[8][4];
#pragma unroll
    for (int i = 0; i < 8; ++i)
#pragma unroll
        for (int p = 0; p < 4; ++p)
            acc[i][p] = (f32x4)0.0f;

    short8 av[8], bv[4];
    f32x4 sS[8];

#pragma unroll 1
    for (int kt = 0; kt < 7; ++kt) {
        const char* rb = smem + (kt & 1) * 65536;
        char* wb       = smem + ((kt + 1) & 1) * 65536;

        FISSUE(sS, Bs, kt + 1);
        FKK(rb, 0);
        asm volatile("s_waitcnt vmcnt(0)" ::: "memory");
        FWRITEB(sS, wb, 32768);
        FISSUE(sS, As, kt + 1);
        FKK(rb, 1);
        asm volatile("s_waitcnt vmcnt(0)" ::: "memory");
        FWRITEB(sS, wb, 0);
        asm volatile("s_waitcnt lgkmcnt(0)" ::: "memory");
        __builtin_amdgcn_sched_barrier(0);
        __builtin_amdgcn_s_barrier();
    }
    {
        const char* rb = smem + 65536;
        FKK(rb, 0);
        FKK(rb, 1);
    }

    const int nc = lane & 15;
    const int kq = lane >> 4;
    float b1v[4], w2v[4];
#pragma unroll
    for (int pp = 0; pp < 4; ++pp) {
        int n = nt * 256 + (wn * 4 + pp) * 16 + nc;
        b1v[pp] = B1[km * 512 + n];
        w2v[pp] = W2[km * 512 + n];
    }

    float* lout = (float*)smem;
#pragma unroll
    for (int i = 0; i < 8; ++i) {
#pragma unroll
        for (int r = 0; r < 4; ++r) {
            float s = 0.f;
#pragma unroll
            for (int pp = 0; pp < 4; ++pp) {
                float h = acc[i][pp][r] + b1v[pp];
                h = h > 0.f ? h : 0.f;
                s += h * w2v[pp];
            }
#pragma unroll
            for (int d = 1; d < 16; d <<= 1)
                s += __shfl_xor(s, d, 64);
            if (nc == 0) {
                int row = wm * 128 + i * 16 + kq * 4 + r;
                lout[row * 4 + wn] = s;
            }
        }
    }
    __syncthreads();
    if (t < 256) {
        float s = lout[t * 4 + 0] + lout[t * 4 + 1] + lout[t * 4 + 2] + lout[t * 4 + 3];
        if (nt == 0) s += B2[km];
        int b = mt * 256 + t;
        atomicAdd(out + (size_t)b * 512 + (km & 7) * 64 + (km >> 3), s);
    }
}

extern "C" void kernel_launch(void* const* d_in, const int* in_sizes, int n_in,
                              void* d_out, int out_size, void* d_ws, size_t ws_size,
                              hipStream_t stream) {
    const float* X  = (const float*)d_in[0];
    const float* W1 = (const float*)d_in[1];
    const float* B1 = (const float*)d_in[2];
    const float* W2 = (const float*)d_in[3];
    const float* B2 = (const float*)d_in[4];
    float* out = (float*)d_out;

    hipMemsetAsync(out, 0, (size_t)out_size * sizeof(float), stream);

    const size_t NEED = 269484032ull;  // W1b 268MB + Xb 1MB (bf16, granule order)
    if (ws_size >= NEED) {
        short* WS = (short*)d_ws;
        ens_cvt<<<dim3(4112), dim3(256), 0, stream>>>(X, W1, WS);
        ens_gemm_direct<<<dim3(4096), dim3(512), 0, stream>>>(
            WS + 134217728ull, WS, B1, W2, B2, out);
    } else {
        ens_mlp_fallback<<<dim3(4096), dim3(512), 131072, stream>>>(
            X, W1, B1, W2, B2, out);
    }
}

// Round 12
// 473.802 us; speedup vs baseline: 1.0967x; 1.0967x over previous
//
#include <hip/hip_runtime.h>
#include <hip/hip_bf16.h>

typedef __attribute__((ext_vector_type(8))) short short8;
typedef __attribute__((ext_vector_type(4))) float f32x4;

// pack 8 fp32 -> 8 bf16 (RNE) as one short8 (4 VGPRs)
__device__ __forceinline__ short8 pack8(const f32x4& a, const f32x4& b) {
    union { __hip_bfloat162 h[4]; short8 s; } u;
    u.h[0] = __float22bfloat162_rn(make_float2(a[0], a[1]));
    u.h[1] = __float22bfloat162_rn(make_float2(a[2], a[3]));
    u.h[2] = __float22bfloat162_rn(make_float2(b[0], b[1]));
    u.h[3] = __float22bfloat162_rn(make_float2(b[2], b[3]));
    return u.s;
}

// r2..r7-proven involution swizzle (fallback kernel only)
__device__ __forceinline__ int swz4(int g) { return g ^ (((g >> 4) & 3) << 1); }

// async global->LDS DMA, 16B per lane; LDS dest = wave-uniform base + lane*16
#define GLDS(GP, LP)                                                          \
    __builtin_amdgcn_global_load_lds(                                         \
        (__attribute__((address_space(1))) void*)(void*)(GP),                 \
        (__attribute__((address_space(3))) void*)(void*)(LP), 16, 0, 0)

// ============================================================================
// Kernel 1 (r8/r9-proven): fp32 -> bf16 conversion + MFMA-granule relayout.
// Granule (idx, ks) = 1KB: lane l holds row idx*16+(l&15), k ks*32+(l>>4)*8..+8.
// W1b: [km][f 0..31][ks 0..15]; Xb (at +134217728 shorts): [mf 0..63][ks].
// ============================================================================
__global__ __launch_bounds__(256)
void ens_cvt(const float* __restrict__ X, const float* __restrict__ W1,
             short* __restrict__ WS)
{
    const int t = threadIdx.x, lane = t & 63, wv = t >> 6;
    const int g = blockIdx.x * 4 + wv;
    const int row16 = lane & 15, koct = lane >> 4;
    const float* src;
    short* dst;
    if (blockIdx.x < 4096) {                       // W1: g = km*32 + f
        const int km = g >> 5, f = g & 31;
        src = W1 + (size_t)km * 262144 + (size_t)(f * 16 + row16) * 512 + koct * 8;
        dst = WS + (size_t)km * 262144 + (size_t)(f * 16) * 512 + lane * 8;
    } else {                                       // X: mf = g - 16384 (0..63)
        const int mf = g - 16384;
        src = X + (size_t)(mf * 16 + row16) * 512 + koct * 8;
        dst = WS + 134217728ull + (size_t)(mf * 16) * 512 + lane * 8;
    }
#pragma unroll
    for (int ks = 0; ks < 16; ++ks) {
        f32x4 a = *(const f32x4*)(src + ks * 32);
        f32x4 b = *(const f32x4*)(src + ks * 32 + 4);
        *(short8*)(dst + ks * 512) = pack8(a, b);
    }
}

// ============================================================================
// Kernel 2: r9 DMA base + REGISTER-PIPELINED phases (the m201 "lgkmcnt(8)"
// mechanism). Per K-tile (BK=64), 4 phases; ds_reads for phase p+1 are issued
// BEFORE phase p's MFMA burst, so the CU-wide LDS drain (~600 cyc) runs UNDER
// the 620-cyc MFMA burst instead of serializing with it. Counted lgkmcnt
// (4/8/4/0) waits only the reads needed now. ONE barrier per K-tile.
// Race audit: GLDS(kt+1) -> buf^1 while reads hit buf; every wave drains its
// reads (ph3 lgkmcnt(0)) and its GLDS (vmcnt(0)) BEFORE the tile barrier, so
// after the barrier: (a) kt+1's staging is visible to all, (b) nobody still
// reads buf when GLDS(kt+2) starts overwriting it next tile. Counted-lgkm
// integrity: read groups are pinned in issue order by sched_barrier(0); no
// other lgkm ops (GLDS counts vmcnt only) are issued in the loop.
// Registers: acc 128 + av 3x16 + bv 2x16 + ptrs ~= 240 unified (<=256 @2w/SIMD).
// ============================================================================
#define SB __builtin_amdgcn_sched_barrier(0)

#define RDA4(DST, MI0, KKV)                                                   \
    _Pragma("unroll") for (int ii = 0; ii < 4; ++ii)                          \
        DST[ii] = *(const short8*)(rb +                                       \
            (((wm * 8 + (MI0) + ii) * 2 + (KKV)) << 10) + l16);

#define RDB4(DST, KKV)                                                        \
    _Pragma("unroll") for (int pp = 0; pp < 4; ++pp)                          \
        DST[pp] = *(const short8*)(rb + 32768 +                               \
            (((wn * 4 + pp) * 2 + (KKV)) << 10) + l16);

#define MFMA16(AV, BV, AOFF)                                                  \
    __builtin_amdgcn_s_setprio(1);                                            \
    _Pragma("unroll") for (int ii = 0; ii < 4; ++ii)                          \
        _Pragma("unroll") for (int pp = 0; pp < 4; ++pp)                      \
            acc[(AOFF) + ii][pp] = __builtin_amdgcn_mfma_f32_16x16x32_bf16(   \
                AV[ii], BV[pp], acc[(AOFF) + ii][pp], 0, 0, 0);               \
    __builtin_amdgcn_s_setprio(0);

// staging: wave's 8 granules; src offsets (shorts) {0,512,8192,8704} +16384*b
#define GLDS4A(KOFF)                                                          \
    GLDS(gsrc + (KOFF) + 0,     wdst + 0);                                    \
    GLDS(gsrc + (KOFF) + 512,   wdst + 1024);                                 \
    GLDS(gsrc + (KOFF) + 8192,  wdst + 2048);                                 \
    GLDS(gsrc + (KOFF) + 8704,  wdst + 3072);

#define GLDS4B(KOFF)                                                          \
    GLDS(gsrc + (KOFF) + 16384, wdst + 4096);                                 \
    GLDS(gsrc + (KOFF) + 16896, wdst + 5120);                                 \
    GLDS(gsrc + (KOFF) + 24576, wdst + 6144);                                 \
    GLDS(gsrc + (KOFF) + 25088, wdst + 7168);

__global__ __launch_bounds__(512, 2)
void ens_gemm_dma(const short* __restrict__ Xb, const short* __restrict__ W1b,
                  const float* __restrict__ B1, const float* __restrict__ W2,
                  const float* __restrict__ B2, float* __restrict__ out)
{
    extern __shared__ char smem[];
    const int t    = threadIdx.x;
    const int lane = t & 63;
    const int l16  = lane << 4;
    const int wv   = t >> 6;
    const int wm   = wv >> 2;     // 0..1
    const int wn   = wv & 3;      // 0..3

    // XCD-aware decode: 8 blocks of the same km adjacent on one XCD.
    const int bb  = blockIdx.x;
    const int xcd = bb & 7;
    const int j   = bb >> 3;
    const int km  = xcd * 64 + (j >> 3);   // 0..511
    const int sub = j & 7;
    const int mt  = sub >> 1;              // 0..3 (256-row batch tile)
    const int nt  = sub & 1;               // 0..1 (256-col n half)

    // Per-wave staging base: waves 0-3 stage A (4 consecutive 16-row groups),
    // waves 4-7 stage B. One pointer + compile-time offsets (q>>1)*8192 +
    // (q&1)*512 covers the wave's 8 granules; LDS dest = wvoff + q*1024.
    const short* gsrc;
    int wvoff;
    if (wv < 4) {
        gsrc  = Xb + (size_t)(mt * 16 + wv * 4) * 8192 + lane * 8;
        wvoff = wv * 8192;
    } else {
        gsrc  = W1b + (size_t)km * 262144 +
                (size_t)(nt * 16 + (wv - 4) * 4) * 8192 + lane * 8;
        wvoff = 32768 + (wv - 4) * 8192;
    }

    f32x4 acc[8][4];
#pragma unroll
    for (int i = 0; i < 8; ++i)
#pragma unroll
        for (int p = 0; p < 4; ++p)
            acc[i][p] = (f32x4)0.0f;

    short8 avP[4], avQ[4], avR[4];   // 3 rotating A-fragment sets (rule #20)
    short8 bvP[4], bvQ[4];           // 2 B-fragment sets

    // ---- prologue: stage tile 0 into buf0, drain, publish ----
    {
        char* wdst = smem + wvoff;
        GLDS4A(0);
        GLDS4B(0);
        asm volatile("s_waitcnt vmcnt(0)" ::: "memory");
        SB;
        __builtin_amdgcn_s_barrier();
    }

#pragma unroll 1
    for (int kt = 0; kt < 8; ++kt) {
        const char* rb = smem + (kt & 1) * 65536;
        char* wdst     = smem + ((kt + 1) & 1) * 65536 + wvoff;
        const int koff = (kt + 1) << 10;   // shorts: next tile's granule pair
        const bool stage = (kt < 7);

        // ph0: issue Q0(avP,kk0)+bK0(bvP) then Q1(avQ,kk0); MFMA Q0
        RDA4(avP, 0, 0);
        RDB4(bvP, 0);
        SB;
        RDA4(avQ, 4, 0);
        SB;
        if (stage) { GLDS4A(koff); }
        asm volatile("s_waitcnt lgkmcnt(4)" ::: "memory");
        SB;
        MFMA16(avP, bvP, 0);
        SB;

        // ph1: issue Q2(avR,kk1)+bK1(bvQ); MFMA Q1
        RDA4(avR, 0, 1);
        RDB4(bvQ, 1);
        SB;
        if (stage) { GLDS4B(koff); }
        asm volatile("s_waitcnt lgkmcnt(8)" ::: "memory");
        SB;
        MFMA16(avQ, bvP, 4);
        SB;

        // ph2: issue Q3(avP reused, kk1); MFMA Q2
        RDA4(avP, 4, 1);
        SB;
        asm volatile("s_waitcnt lgkmcnt(4)" ::: "memory");
        SB;
        MFMA16(avR, bvQ, 0);
        SB;

        // ph3: drain reads + staging; MFMA Q3; tile barrier
        asm volatile("s_waitcnt lgkmcnt(0)" ::: "memory");
        if (stage) { asm volatile("s_waitcnt vmcnt(0)" ::: "memory"); }
        SB;
        MFMA16(avP, bvQ, 4);
        SB;
        __builtin_amdgcn_s_barrier();
    }

    // ---- fused epilogue (r6-proven): relu + dot(W2) partials + scatter ----
    const int nc = lane & 15;
    const int kq = lane >> 4;
    float b1v[4], w2v[4];
#pragma unroll
    for (int pp = 0; pp < 4; ++pp) {
        int n = nt * 256 + (wn * 4 + pp) * 16 + nc;
        b1v[pp] = B1[km * 512 + n];
        w2v[pp] = W2[km * 512 + n];
    }

    float* lout = (float*)smem;   // buf0; all LDS reads drained at tile barriers
#pragma unroll
    for (int i = 0; i < 8; ++i) {
#pragma unroll
        for (int r = 0; r < 4; ++r) {
            float s = 0.f;
#pragma unroll
            for (int pp = 0; pp < 4; ++pp) {
                float h = acc[i][pp][r] + b1v[pp];
                h = h > 0.f ? h : 0.f;
                s += h * w2v[pp];
            }
#pragma unroll
            for (int d = 1; d < 16; d <<= 1)
                s += __shfl_xor(s, d, 64);
            if (nc == 0) {
                int row = wm * 128 + i * 16 + kq * 4 + r;
                lout[row * 4 + wn] = s;
            }
        }
    }
    __syncthreads();
    if (t < 256) {
        float s = lout[t * 4 + 0] + lout[t * 4 + 1] + lout[t * 4 + 2] + lout[t * 4 + 3];
        if (nt == 0) s += B2[km];
        int b = mt * 256 + t;
        // out[b, e, o] with k = o*E + e  ->  flat b*512 + (km%8)*64 + (km/8)
        atomicAdd(out + (size_t)b * 512 + (km & 7) * 64 + (km >> 3), s);
    }
}

// ============================================================================
// Fallback (r6 verbatim, 428 µs): used when ws_size < 269,484,032 bytes.
// ============================================================================
#define FISSUE(S, BASE, KT1)                                                  \
  do {                                                                        \
    const float* q_ = (BASE) + (KT1) * 64;                                    \
    S[0] = *(const f32x4*)q_;          S[1] = *(const f32x4*)(q_ + 4);        \
    S[2] = *(const f32x4*)(q_ + 32);   S[3] = *(const f32x4*)(q_ + 36);       \
    const float* q2_ = q_ + 65536;                                            \
    S[4] = *(const f32x4*)q2_;         S[5] = *(const f32x4*)(q2_ + 4);       \
    S[6] = *(const f32x4*)(q2_ + 32);  S[7] = *(const f32x4*)(q2_ + 36);      \
  } while (0)

#define FWRITEB(S, WB, OPOFF)                                                 \
  do {                                                                        \
    char* d0_ = (WB) + (OPOFF) + wfrag;                                       \
    *(short8*)d0_ = pack8(S[0], S[1]);                                        \
    *(short8*)(d0_ + 1024) = pack8(S[2], S[3]);                               \
    char* d1_ = d0_ + 16384;                                                  \
    *(short8*)d1_ = pack8(S[4], S[5]);                                        \
    *(short8*)(d1_ + 1024) = pack8(S[6], S[7]);                               \
  } while (0)

#define FKK(RB, KKV)                                                          \
  do {                                                                        \
    _Pragma("unroll") for (int mi = 0; mi < 8; ++mi)                          \
        av[mi] = *(const short8*)((RB) +                                      \
            (((wm * 8 + mi) * 2 + (KKV)) << 10) + rdo);                       \
    _Pragma("unroll") for (int pp = 0; pp < 4; ++pp)                          \
        bv[pp] = *(const short8*)((RB) + 32768 +                              \
            (((wn * 4 + pp) * 2 + (KKV)) << 10) + rdo);                       \
    __builtin_amdgcn_s_setprio(1);                                            \
    _Pragma("unroll") for (int mi = 0; mi < 8; ++mi)                          \
        _Pragma("unroll") for (int pp = 0; pp < 4; ++pp)                      \
            acc[mi][pp] = __builtin_amdgcn_mfma_f32_16x16x32_bf16(            \
                av[mi], bv[pp], acc[mi][pp], 0, 0, 0);                        \
    __builtin_amdgcn_s_setprio(0);                                            \
  } while (0)

#define FPRO_WRITE(TT, ROFF)                                                  \
  do {                                                                        \
    short8 a_ = pack8(TT[0], TT[1]);                                          \
    short8 b_ = pack8(TT[2], TT[3]);                                          \
    char* d_ = smem + (ROFF) + wfrag;                                         \
    *(short8*)d_ = a_;                                                        \
    *(short8*)(d_ + 1024) = b_;                                               \
  } while (0)

__global__ __launch_bounds__(512, 2)
void ens_mlp_fallback(const float* __restrict__ X,
                      const float* __restrict__ W1,
                      const float* __restrict__ B1,
                      const float* __restrict__ W2,
                      const float* __restrict__ B2,
                      float* __restrict__ out)
{
    extern __shared__ char smem[];
    const int t    = threadIdx.x;
    const int lane = t & 63;
    const int wv   = t >> 6;
    const int wm   = wv >> 2;
    const int wn   = wv & 3;

    const int bb  = blockIdx.x;
    const int xcd = bb & 7;
    const int j   = bb >> 3;
    const int km  = xcd * 64 + (j >> 3);
    const int sub = j & 7;
    const int mt  = sub >> 1;
    const int nt  = sub & 1;

    const float* __restrict__ W1k = W1 + (size_t)km * (512 * 512);

    const int lr = t >> 2;
    const int c  = t & 3;
    const float* As = X   + (size_t)(mt * 256 + lr) * 512 + c * 8;
    const float* Bs = W1k + (size_t)(nt * 256 + lr) * 512 + c * 8;
    const int wfrag = ((lr >> 4) << 11) + (swz4((c << 4) | (lr & 15)) << 4);
    const int rdo   = swz4(lane) << 4;

    {
        f32x4 t0[4], t1[4], t2[4], t3[4];
        const float* q;
        q = As;          t0[0]=*(const f32x4*)q; t0[1]=*(const f32x4*)(q+4); t0[2]=*(const f32x4*)(q+32); t0[3]=*(const f32x4*)(q+36);
        q = As + 65536;  t1[0]=*(const f32x4*)q; t1[1]=*(const f32x4*)(q+4); t1[2]=*(const f32x4*)(q+32); t1[3]=*(const f32x4*)(q+36);
        q = Bs;          t2[0]=*(const f32x4*)q; t2[1]=*(const f32x4*)(q+4); t2[2]=*(const f32x4*)(q+32); t2[3]=*(const f32x4*)(q+36);
        q = Bs + 65536;  t3[0]=*(const f32x4*)q; t3[1]=*(const f32x4*)(q+4); t3[2]=*(const f32x4*)(q+32); t3[3]=*(const f32x4*)(q+36);
        asm volatile("s_waitcnt vmcnt(12)" ::: "memory"); FPRO_WRITE(t0, 0);
        asm volatile("s_waitcnt vmcnt(8)"  ::: "memory"); FPRO_WRITE(t1, 16384);
        asm volatile("s_waitcnt vmcnt(4)"  ::: "memory"); FPRO_WRITE(t2, 32768);
        asm volatile("s_waitcnt vmcnt(0)"  ::: "memory"); FPRO_WRITE(t3, 49152);
        asm volatile("s_waitcnt lgkmcnt(0)" ::: "memory");
        __builtin_amdgcn_sched_barrier(0);
        __builtin_amdgcn_s_barrier();
    }

    f32x4 acc[8][4];
#pragma unroll
    for (int i = 0; i < 8; ++i)
#pragma unroll
        for (int p = 0; p < 4; ++p)
            acc[i][p] = (f32x4)0.0f;

    short8 av[8], bv[4];
    f32x4 sS[8];

#pragma unroll 1
    for (int kt = 0; kt < 7; ++kt) {
        const char* rb = smem + (kt & 1) * 65536;
        char* wb       = smem + ((kt + 1) & 1) * 65536;

        FISSUE(sS, Bs, kt + 1);
        FKK(rb, 0);
        asm volatile("s_waitcnt vmcnt(0)" ::: "memory");
        FWRITEB(sS, wb, 32768);
        FISSUE(sS, As, kt + 1);
        FKK(rb, 1);
        asm volatile("s_waitcnt vmcnt(0)" ::: "memory");
        FWRITEB(sS, wb, 0);
        asm volatile("s_waitcnt lgkmcnt(0)" ::: "memory");
        __builtin_amdgcn_sched_barrier(0);
        __builtin_amdgcn_s_barrier();
    }
    {
        const char* rb = smem + 65536;
        FKK(rb, 0);
        FKK(rb, 1);
    }

    const int nc = lane & 15;
    const int kq = lane >> 4;
    float b1v[4], w2v[4];
#pragma unroll
    for (int pp = 0; pp < 4; ++pp) {
        int n = nt * 256 + (wn * 4 + pp) * 16 + nc;
        b1v[pp] = B1[km * 512 + n];
        w2v[pp] = W2[km * 512 + n];
    }

    float* lout = (float*)smem;
#pragma unroll
    for (int i = 0; i < 8; ++i) {
#pragma unroll
        for (int r = 0; r < 4; ++r) {
            float s = 0.f;
#pragma unroll
            for (int pp = 0; pp < 4; ++pp) {
                float h = acc[i][pp][r] + b1v[pp];
                h = h > 0.f ? h : 0.f;
                s += h * w2v[pp];
            }
#pragma unroll
            for (int d = 1; d < 16; d <<= 1)
                s += __shfl_xor(s, d, 64);
            if (nc == 0) {
                int row = wm * 128 + i * 16 + kq * 4 + r;
                lout[row * 4 + wn] = s;
            }
        }
    }
    __syncthreads();
    if (t < 256) {
        float s = lout[t * 4 + 0] + lout[t * 4 + 1] + lout[t * 4 + 2] + lout[t * 4 + 3];
        if (nt == 0) s += B2[km];
        int b = mt * 256 + t;
        atomicAdd(out + (size_t)b * 512 + (km & 7) * 64 + (km >> 3), s);
    }
}

extern "C" void kernel_launch(void* const* d_in, const int* in_sizes, int n_in,
                              void* d_out, int out_size, void* d_ws, size_t ws_size,
                              hipStream_t stream) {
    const float* X  = (const float*)d_in[0];
    const float* W1 = (const float*)d_in[1];
    const float* B1 = (const float*)d_in[2];
    const float* W2 = (const float*)d_in[3];
    const float* B2 = (const float*)d_in[4];
    float* out = (float*)d_out;

    hipMemsetAsync(out, 0, (size_t)out_size * sizeof(float), stream);

    const size_t NEED = 269484032ull;  // W1b 268MB + Xb 1MB (bf16, granule order)
    if (ws_size >= NEED) {
        short* WS = (short*)d_ws;
        ens_cvt<<<dim3(4112), dim3(256), 0, stream>>>(X, W1, WS);
        ens_gemm_dma<<<dim3(4096), dim3(512), 131072, stream>>>(
            WS + 134217728ull, WS, B1, W2, B2, out);
    } else {
        ens_mlp_fallback<<<dim3(4096), dim3(512), 131072, stream>>>(
            X, W1, B1, W2, B2, out);
    }
}